// Round 4
// baseline (753.286 us; speedup 1.0000x reference)
//
#include <hip/hip_runtime.h>
#include <hip/hip_bf16.h>
#include <cstddef>
#include <cstdint>

// ---------------------------------------------------------------------------
// CascadeRCNN head, round 4:
//   ROIAlign: per-(roi,channel) footprint staged ONCE into LDS with dense
//     coalesced loads (TA-transaction fix); samples computed from LDS with
//     per-lane hoisted addresses/weights; bin-combine via LDS sample buffer.
//   fc1/fc2 via bf16x3-split MFMA GEMM (m97 structure + split-K)
//   reduce kernel fuses split-K sum + bias + relu + next-layer hi/lo split
//   predictor in fp32 (tiny)
// ---------------------------------------------------------------------------

#define NROIS 1024
#define C_CH  256
#define OUTP  7
#define DFEAT (C_CH * OUTP * OUTP)   // 12544
#define HID   1024
#define NCLS  20

#define FP_CAP 1152                  // worst-case footprint floats (<=~1020 + pad)

// ---------------- bf16 helpers (RTNE) ----------------
__device__ __forceinline__ unsigned short f2bf(float x) {
    union { float f; uint32_t u; } v; v.f = x;
    uint32_t r = v.u + 0x7fffu + ((v.u >> 16) & 1u);
    return (unsigned short)(r >> 16);
}
__device__ __forceinline__ float bf2f(unsigned short h) {
    union { uint32_t u; float f; } v; v.u = ((uint32_t)h) << 16;
    return v.f;
}

// ---------------- async global->LDS (16B/lane) ----------------
__device__ __forceinline__ void g2lds16(const void* g, void* l) {
    __builtin_amdgcn_global_load_lds(
        (const __attribute__((address_space(1))) void*)g,
        (__attribute__((address_space(3))) void*)l,
        16, 0, 0);
}

typedef __attribute__((ext_vector_type(8))) short bf16x8;
typedef __attribute__((ext_vector_type(4))) float f32x4;

// ------------------------------- ROI ALIGN ---------------------------------
// grid (NROIS, 2): blockIdx.x = roi, blockIdx.y = channel half.
// 256 threads = 4 waves; wave handles 32 channels independently in its own
// LDS slice. Per channel: stage footprint (dense), 196 bilinear samples from
// LDS, 2x2 bin combine through a 196-float LDS buffer, store bf16 hi/lo.
__global__ __launch_bounds__(256) void roi_pool_lds(
    const float* __restrict__ fm0, const float* __restrict__ fm1,
    const float* __restrict__ fm2, const float* __restrict__ fm3,
    const float* __restrict__ rois,
    unsigned short* __restrict__ ph, unsigned short* __restrict__ pl)
{
    const int roi = blockIdx.x;
    const int t   = threadIdx.x;

    __shared__ float s_box[5];
    __shared__ int   s_ix0[16], s_ix1[16], s_iy0[16], s_iy1[16];
    __shared__ float s_wx0[16], s_wx1[16], s_wy0[16], s_wy1[16];
    __shared__ __align__(16) float s_fp[4][FP_CAP];
    __shared__ __align__(16) float s_samp[4][200];

    if (t < 5) s_box[t] = rois[(size_t)roi * 5 + t];
    __syncthreads();

    const int   b   = (int)s_box[0];
    const float bx1 = s_box[1], by1 = s_box[2], bx2 = s_box[3], by2 = s_box[4];

    const float w = bx2 - bx1, h = by2 - by1;
    float kf = floorf(4.0f + log2f(sqrtf(fmaxf(w * h, 1e-6f)) / 224.0f));
    kf = fminf(fmaxf(kf, 2.0f), 5.0f);
    const int lvl    = (int)kf - 2;
    const int stride = 4 << lvl;
    const int H  = 768  / stride;
    const int Wd = 1280 / stride;
    const float* fm = (lvl == 0) ? fm0 : (lvl == 1) ? fm1 : (lvl == 2) ? fm2 : fm3;

    if (t < 14) {
        const float x1s = bx1 / (float)stride - 0.5f;
        const float x2s = bx2 / (float)stride - 0.5f;
        const float coord = x1s + (x2s - x1s) * (((float)t + 0.5f) / 14.0f);
        const float valid = (coord > -1.0f && coord < (float)Wd) ? 1.0f : 0.0f;
        const float cc = fminf(fmaxf(coord, 0.0f), (float)(Wd - 1));
        const int i0 = (int)floorf(cc);
        s_ix0[t] = i0; s_ix1[t] = min(i0 + 1, Wd - 1);
        const float fr = cc - (float)i0;
        s_wx0[t] = (1.0f - fr) * valid; s_wx1[t] = fr * valid;
    } else if (t >= 16 && t < 30) {
        const int j = t - 16;
        const float y1s = by1 / (float)stride - 0.5f;
        const float y2s = by2 / (float)stride - 0.5f;
        const float coord = y1s + (y2s - y1s) * (((float)j + 0.5f) / 14.0f);
        const float valid = (coord > -1.0f && coord < (float)H) ? 1.0f : 0.0f;
        const float cc = fminf(fmaxf(coord, 0.0f), (float)(H - 1));
        const int i0 = (int)floorf(cc);
        s_iy0[j] = i0; s_iy1[j] = min(i0 + 1, H - 1);
        const float fr = cc - (float)i0;
        s_wy0[j] = (1.0f - fr) * valid; s_wy1[j] = fr * valid;
    }
    __syncthreads();

    // footprint rectangle (indices are monotone + clamped in-range)
    const int xmin = s_ix0[0], xmax = s_ix1[13];
    const int ymin = s_iy0[0], ymax = s_iy1[13];
    const int rowlen = xmax - xmin + 1;
    const int rows   = ymax - ymin + 1;

    const int wv = t >> 6, lane = t & 63;
    float* fpw   = s_fp[wv];
    float* sampw = s_samp[wv];

    // ---- per-lane hoisted sample data (invariant across channels) ----
    int   a00[4], a01[4], a10[4], a11[4];
    float w00[4], w01[4], w10[4], w11[4];
    bool  sval[4];
    #pragma unroll
    for (int j = 0; j < 4; ++j) {
        const int s = j * 64 + lane;
        const bool v = (s < 196);
        sval[j] = v;
        const int ss = v ? s : 0;
        const int jy = ss / 14;
        const int jx = ss - jy * 14;
        const int ro0 = (s_iy0[jy] - ymin) * rowlen;
        const int ro1 = (s_iy1[jy] - ymin) * rowlen;
        const int lx0 = s_ix0[jx] - xmin;
        const int lx1 = s_ix1[jx] - xmin;
        a00[j] = ro0 + lx0; a01[j] = ro0 + lx1;
        a10[j] = ro1 + lx0; a11[j] = ro1 + lx1;
        const float wy0 = s_wy0[jy], wy1 = s_wy1[jy];
        const float wx0 = s_wx0[jx], wx1 = s_wx1[jx];
        w00[j] = wy0 * wx0; w01[j] = wy0 * wx1;
        w10[j] = wy1 * wx0; w11[j] = wy1 * wx1;
    }

    // combine-phase hoists (lanes 0..48)
    const int bin = lane;
    const int by = bin / 7, bx = bin - by * 7;
    const int s00 = 28 * by + 2 * bx;
    const bool bact = (bin < 49);

    // staging lane mapping: lpr lanes per row, rpi rows per iteration
    const int lpr_sh = (rowlen > 16) ? 5 : (rowlen > 8 ? 4 : 3);
    const int lpr = 1 << lpr_sh;
    const int rpi = 64 >> lpr_sh;
    const int rlane = lane >> lpr_sh;
    const int clane = lane & (lpr - 1);

    const size_t hw = (size_t)H * Wd;
    const float* fmb = fm + (size_t)b * C_CH * hw;
    const int c0w = blockIdx.y * 128 + wv * 32;

    size_t obase = (size_t)roi * DFEAT + (size_t)c0w * 49 + bin;

    for (int ci = 0; ci < 32; ++ci) {
        const int c = c0w + ci;
        const float* fb = fmb + (size_t)c * hw + (size_t)ymin * Wd + xmin;

        // ---- stage footprint (dense, coalesced) ----
        for (int r = 0; r < rows; r += rpi) {
            const int rr = r + rlane;
            const bool rok = (rr < rows);
            const float* gsrc = fb + (size_t)rr * Wd;
            float* ldst = fpw + rr * rowlen;
            for (int cc0 = 0; cc0 < rowlen; cc0 += lpr) {
                const int cc = cc0 + clane;
                if (rok && cc < rowlen) ldst[cc] = gsrc[cc];
            }
        }
        __syncthreads();

        // ---- 196 bilinear samples from LDS ----
        #pragma unroll
        for (int j = 0; j < 4; ++j) {
            const float v = w00[j] * fpw[a00[j]] + w01[j] * fpw[a01[j]]
                          + w10[j] * fpw[a10[j]] + w11[j] * fpw[a11[j]];
            if (sval[j]) sampw[j * 64 + lane] = v;
        }
        __syncthreads();

        // ---- 2x2 bin combine + bf16 hi/lo store ----
        if (bact) {
            const float r = 0.25f * (sampw[s00] + sampw[s00 + 1]
                                   + sampw[s00 + 14] + sampw[s00 + 15]);
            const unsigned short hh = f2bf(r);
            ph[obase] = hh;
            pl[obase] = f2bf(r - bf2f(hh));
        }
        obase += 49;
    }
}

// ------------------------- fp32 -> bf16 hi/lo split -------------------------
__global__ __launch_bounds__(256) void split_fp32_bf16(
    const float* __restrict__ w, unsigned short* __restrict__ h,
    unsigned short* __restrict__ l, int n4)
{
    int i = blockIdx.x * 256 + threadIdx.x;
    const int stride = gridDim.x * 256;
    for (; i < n4; i += stride) {
        const float4 v = *(const float4*)(w + (size_t)i * 4);
        ushort4 hh, ll;
        hh.x = f2bf(v.x); ll.x = f2bf(v.x - bf2f(hh.x));
        hh.y = f2bf(v.y); ll.y = f2bf(v.y - bf2f(hh.y));
        hh.z = f2bf(v.z); ll.z = f2bf(v.z - bf2f(hh.z));
        hh.w = f2bf(v.w); ll.w = f2bf(v.w - bf2f(hh.w));
        *(ushort4*)(h + (size_t)i * 4) = hh;
        *(ushort4*)(l + (size_t)i * 4) = ll;
    }
}

// --------------------------- bf16x3 MFMA GEMM ------------------------------
// part[z][m][n] (no bias) = sum over k-slice of (Ah+Al)(Wh+Wl)^T, dropping Al*Wl.
// M = N = 1024 fixed. 128x128 tile, BK=32, 256 thr = 4 waves, each wave 64x64
// (4x4 frags of 16x16x32). global_load_lds 16B staging, ds_read_b128 frags.
#define GBM 128
#define GBN 128
#define GBK 32

__global__ __launch_bounds__(256) void gemm_bf16x3(
    const unsigned short* __restrict__ Ah, const unsigned short* __restrict__ Al,
    const unsigned short* __restrict__ Bh, const unsigned short* __restrict__ Bl,
    float* __restrict__ part, int K, int ksplit)
{
    __shared__ __align__(16) unsigned short sAh[GBM * GBK];
    __shared__ __align__(16) unsigned short sAl[GBM * GBK];
    __shared__ __align__(16) unsigned short sBh[GBN * GBK];
    __shared__ __align__(16) unsigned short sBl[GBN * GBK];

    const int t  = threadIdx.x;
    const int bm = blockIdx.y * GBM, bn = blockIdx.x * GBN;
    const int k0 = blockIdx.z * ksplit, k1 = k0 + ksplit;
    const int lane = t & 63, wv = t >> 6;
    const int wr = wv >> 1, wc = wv & 1;
    const int lm = lane & 15, quad = lane >> 4;

    f32x4 acc[4][4] = {};

    const int srow = t >> 2;        // staging row 0..63 (+q*64)
    const int skc  = (t & 3) * 8;   // staging k offset (elements)

    for (int kk = k0; kk < k1; kk += GBK) {
        #pragma unroll
        for (int q = 0; q < 2; ++q) {
            const int row = q * 64 + srow;
            const size_t ga = (size_t)(bm + row) * K + kk + skc;
            const size_t gb = (size_t)(bn + row) * K + kk + skc;
            const int lo = q * 4096 + t * 16;   // LDS byte offset
            g2lds16(Ah + ga, (char*)sAh + lo);
            g2lds16(Al + ga, (char*)sAl + lo);
            g2lds16(Bh + gb, (char*)sBh + lo);
            g2lds16(Bl + gb, (char*)sBl + lo);
        }
        __syncthreads();

        bf16x8 fah[4], fal[4], fbh[4], fbl[4];
        #pragma unroll
        for (int i = 0; i < 4; ++i) {
            fah[i] = *(const bf16x8*)&sAh[(wr * 64 + i * 16 + lm) * GBK + quad * 8];
            fal[i] = *(const bf16x8*)&sAl[(wr * 64 + i * 16 + lm) * GBK + quad * 8];
            fbh[i] = *(const bf16x8*)&sBh[(wc * 64 + i * 16 + lm) * GBK + quad * 8];
            fbl[i] = *(const bf16x8*)&sBl[(wc * 64 + i * 16 + lm) * GBK + quad * 8];
        }
        #pragma unroll
        for (int i = 0; i < 4; ++i)
            #pragma unroll
            for (int j = 0; j < 4; ++j)
                acc[i][j] = __builtin_amdgcn_mfma_f32_16x16x32_bf16(fah[i], fbh[j], acc[i][j], 0, 0, 0);
        #pragma unroll
        for (int i = 0; i < 4; ++i)
            #pragma unroll
            for (int j = 0; j < 4; ++j)
                acc[i][j] = __builtin_amdgcn_mfma_f32_16x16x32_bf16(fah[i], fbl[j], acc[i][j], 0, 0, 0);
        #pragma unroll
        for (int i = 0; i < 4; ++i)
            #pragma unroll
            for (int j = 0; j < 4; ++j)
                acc[i][j] = __builtin_amdgcn_mfma_f32_16x16x32_bf16(fal[i], fbh[j], acc[i][j], 0, 0, 0);
        __syncthreads();
    }

    float* out = part + (size_t)blockIdx.z * (HID * NROIS);
    #pragma unroll
    for (int i = 0; i < 4; ++i) {
        const int mbase = bm + wr * 64 + i * 16 + quad * 4;
        #pragma unroll
        for (int j = 0; j < 4; ++j) {
            const int n = bn + wc * 64 + j * 16 + lm;
            #pragma unroll
            for (int r = 0; r < 4; ++r)
                out[(size_t)(mbase + r) * HID + n] = acc[i][j][r];
        }
    }
}

// -------- split-K reduce + bias + relu (+ optional hi/lo split out) --------
// mode 0: write fp32 to ofp.  mode 1: write bf16 hi/lo to oh/ol.
__global__ __launch_bounds__(256) void reduce_bias_relu(
    const float* __restrict__ part, const float* __restrict__ bias,
    int S, int mode, unsigned short* __restrict__ oh,
    unsigned short* __restrict__ ol, float* __restrict__ ofp)
{
    const int i4 = blockIdx.x * 256 + threadIdx.x;   // over (1024*1024)/4
    const size_t off = (size_t)i4 * 4;
    const int n = (int)(off & (HID - 1));
    float4 s = *(const float4*)(part + off);
    for (int z = 1; z < S; ++z) {
        const float4 p = *(const float4*)(part + (size_t)z * HID * NROIS + off);
        s.x += p.x; s.y += p.y; s.z += p.z; s.w += p.w;
    }
    const float4 b = *(const float4*)(bias + n);
    s.x = fmaxf(s.x + b.x, 0.0f);
    s.y = fmaxf(s.y + b.y, 0.0f);
    s.z = fmaxf(s.z + b.z, 0.0f);
    s.w = fmaxf(s.w + b.w, 0.0f);
    if (mode == 0) {
        *(float4*)(ofp + off) = s;
    } else {
        ushort4 hh, ll;
        hh.x = f2bf(s.x); ll.x = f2bf(s.x - bf2f(hh.x));
        hh.y = f2bf(s.y); ll.y = f2bf(s.y - bf2f(hh.y));
        hh.z = f2bf(s.z); ll.z = f2bf(s.z - bf2f(hh.z));
        hh.w = f2bf(s.w); ll.w = f2bf(s.w - bf2f(hh.w));
        *(ushort4*)(oh + off) = hh;
        *(ushort4*)(ol + off) = ll;
    }
}

// ------------------------------ PREDICTOR ----------------------------------
__global__ __launch_bounds__(256) void pred_kernel(
    const float* __restrict__ A, const float* __restrict__ Wm,
    const float* __restrict__ bias, float* __restrict__ out)
{
    const int i = blockIdx.x;
    const int t = threadIdx.x;
    const int j = t & 31;
    const int s = t >> 5;

    __shared__ float red[8][32];

    float acc = 0.0f;
    if (j < NCLS) {
        const float4* a4 = (const float4*)(A  + (size_t)i * HID + s * 128);
        const float4* w4 = (const float4*)(Wm + (size_t)j * HID + s * 128);
        #pragma unroll 8
        for (int q = 0; q < 32; ++q) {
            const float4 a = a4[q], w = w4[q];
            acc += a.x * w.x + a.y * w.y + a.z * w.z + a.w * w.w;
        }
    }
    red[s][j] = acc;
    __syncthreads();
    if (s == 0 && j < NCLS) {
        float v = bias[j];
        #pragma unroll
        for (int q = 0; q < 8; ++q) v += red[q][j];
        out[(size_t)i * NCLS + j] = v;
    }
}

// ------------------------------- LAUNCH ------------------------------------
extern "C" void kernel_launch(void* const* d_in, const int* in_sizes, int n_in,
                              void* d_out, int out_size, void* d_ws, size_t ws_size,
                              hipStream_t stream) {
    (void)in_sizes; (void)n_in; (void)out_size;

    const float* fm0   = (const float*)d_in[0];
    const float* fm1   = (const float*)d_in[1];
    const float* fm2   = (const float*)d_in[2];
    const float* fm3   = (const float*)d_in[3];
    const float* rois  = (const float*)d_in[4];
    const float* fc1_w = (const float*)d_in[5];
    const float* fc1_b = (const float*)d_in[6];
    const float* fc2_w = (const float*)d_in[7];
    const float* fc2_b = (const float*)d_in[8];
    const float* p_w   = (const float*)d_in[9];
    const float* p_b   = (const float*)d_in[10];

    // ---- workspace layout ----
    const size_t SZ_POOL = (size_t)NROIS * DFEAT * 2;   // 25.7 MB (bf16)
    const size_t SZ_W1   = (size_t)HID * DFEAT * 2;     // 25.7 MB
    const size_t SZ_W2   = (size_t)HID * HID * 2;       // 2.1 MB
    const size_t SZ_FC1  = (size_t)NROIS * HID * 2;     // 2.1 MB
    const size_t SZ_FC2O = (size_t)NROIS * HID * 4;     // 4.2 MB
    const size_t SZ_PART1 = (size_t)HID * NROIS * 4;    // 4.2 MB per split

    const size_t fixed = 2 * SZ_POOL + 2 * SZ_W1 + 2 * SZ_W2 + 2 * SZ_FC1 + SZ_FC2O;
    int S1 = 8;
    while (S1 > 1 && fixed + (size_t)S1 * SZ_PART1 > ws_size) S1 >>= 1;
    const int S2 = (S1 < 4) ? S1 : 4;

    char* p = (char*)d_ws;
    unsigned short* ph   = (unsigned short*)p; p += SZ_POOL;
    unsigned short* pl   = (unsigned short*)p; p += SZ_POOL;
    unsigned short* w1h  = (unsigned short*)p; p += SZ_W1;
    unsigned short* w1l  = (unsigned short*)p; p += SZ_W1;
    unsigned short* w2h  = (unsigned short*)p; p += SZ_W2;
    unsigned short* w2l  = (unsigned short*)p; p += SZ_W2;
    unsigned short* fc1h = (unsigned short*)p; p += SZ_FC1;
    unsigned short* fc1l = (unsigned short*)p; p += SZ_FC1;
    float* fc2o = (float*)p; p += SZ_FC2O;
    float* part = (float*)p;

    float* outp = (float*)d_out;

    // 1. weight splits
    split_fp32_bf16<<<4096, 256, 0, stream>>>(fc1_w, w1h, w1l, HID * DFEAT / 4);
    split_fp32_bf16<<<1024, 256, 0, stream>>>(fc2_w, w2h, w2l, HID * HID / 4);

    // 2. roi align -> pooled hi/lo  (footprint-staged)
    roi_pool_lds<<<dim3(NROIS, 2), 256, 0, stream>>>(fm0, fm1, fm2, fm3, rois, ph, pl);

    // 3. fc1: [1024,12544] x [1024,12544]^T, split-K S1
    {
        dim3 grid(HID / GBN, NROIS / GBM, S1);
        gemm_bf16x3<<<grid, 256, 0, stream>>>(ph, pl, w1h, w1l, part, DFEAT, DFEAT / S1);
    }
    reduce_bias_relu<<<NROIS * HID / 4 / 256, 256, 0, stream>>>(
        part, fc1_b, S1, 1, fc1h, fc1l, (float*)nullptr);

    // 4. fc2: [1024,1024] x [1024,1024]^T, split-K S2
    {
        dim3 grid(HID / GBN, NROIS / GBM, S2);
        gemm_bf16x3<<<grid, 256, 0, stream>>>(fc1h, fc1l, w2h, w2l, part, HID, HID / S2);
    }
    reduce_bias_relu<<<NROIS * HID / 4 / 256, 256, 0, stream>>>(
        part, fc2_b, S2, 0, (unsigned short*)nullptr, (unsigned short*)nullptr, fc2o);

    // 5. predictor
    pred_kernel<<<NROIS, 256, 0, stream>>>(fc2o, p_w, p_b, outp);
}

// Round 6
// 540.798 us; speedup vs baseline: 1.3929x; 1.3929x over previous
//
#include <hip/hip_runtime.h>
#include <hip/hip_bf16.h>
#include <cstddef>
#include <cstdint>

// ---------------------------------------------------------------------------
// CascadeRCNN head, round 6 (= round 5 + split_permute_w1 grid fix 16->4):
//   fmaps NCHW -> NHWC fp32 (LDS-transposed streaming transform), then
//   ROIAlign with lane=channel (fully coalesced float4 tap loads).
//   Pooled K-order is bin-major (k = bin*256 + c); fc1 weights permuted to
//   match during the hi/lo split. Fallback to gather ROI kernel if ws small.
//   fc1/fc2: bf16x3-split MFMA GEMM + split-K; fused reduce/bias/relu/split.
// ---------------------------------------------------------------------------

#define NROIS 1024
#define C_CH  256
#define OUTP  7
#define DFEAT (C_CH * OUTP * OUTP)   // 12544
#define HID   1024
#define NCLS  20

// NHWC level offsets (floats): B=2, C=256, (H,W) = (192,320)(96,160)(48,80)(24,40)
#define NHWC_OFF0 0
#define NHWC_OFF1 31457280
#define NHWC_OFF2 39321600
#define NHWC_OFF3 41287680
#define NHWC_TOT  41779200

// ---------------- bf16 helpers (RTNE) ----------------
__device__ __forceinline__ unsigned short f2bf(float x) {
    union { float f; uint32_t u; } v; v.f = x;
    uint32_t r = v.u + 0x7fffu + ((v.u >> 16) & 1u);
    return (unsigned short)(r >> 16);
}
__device__ __forceinline__ float bf2f(unsigned short h) {
    union { uint32_t u; float f; } v; v.u = ((uint32_t)h) << 16;
    return v.f;
}

// ---------------- async global->LDS (16B/lane) ----------------
__device__ __forceinline__ void g2lds16(const void* g, void* l) {
    __builtin_amdgcn_global_load_lds(
        (const __attribute__((address_space(1))) void*)g,
        (__attribute__((address_space(3))) void*)l,
        16, 0, 0);
}

typedef __attribute__((ext_vector_type(8))) short bf16x8;
typedef __attribute__((ext_vector_type(4))) float f32x4;

// ------------------------- NCHW -> NHWC transform --------------------------
// grid (xtiles, H, B*4). Tile: 64 channels x 64 x-positions through LDS.
__global__ __launch_bounds__(256) void nchw_to_nhwc(
    const float* __restrict__ in, float* __restrict__ out, int H, int W)
{
    __shared__ float s[64][69];

    const int t  = threadIdx.x;
    const int x0 = blockIdx.x * 64;
    const int y  = blockIdx.y;
    const int ct = blockIdx.z & 3;
    const int b  = blockIdx.z >> 2;
    const int c0 = ct * 64;

    const int tx = t & 15, ty = t >> 4;

    #pragma unroll
    for (int q = 0; q < 4; ++q) {
        const int row = ty + q * 16;
        const int x = x0 + tx * 4;
        if (x < W) {
            const float4 v = *(const float4*)(in +
                (((size_t)(b * C_CH + c0 + row) * H + y) * W + x));
            s[row][tx * 4 + 0] = v.x; s[row][tx * 4 + 1] = v.y;
            s[row][tx * 4 + 2] = v.z; s[row][tx * 4 + 3] = v.w;
        }
    }
    __syncthreads();

    #pragma unroll
    for (int q = 0; q < 4; ++q) {
        const int j = ty + q * 16;
        const int x = x0 + j;
        if (x < W) {
            float4 v;
            v.x = s[tx * 4 + 0][j]; v.y = s[tx * 4 + 1][j];
            v.z = s[tx * 4 + 2][j]; v.w = s[tx * 4 + 3][j];
            *(float4*)(out + (((size_t)(b * H + y) * W + x) * C_CH + c0 + tx * 4)) = v;
        }
    }
}

// ------------------------------- ROI ALIGN (NHWC) --------------------------
// grid (NROIS, 2), 256 thr = 4 waves. lane covers channels lane*4..+3.
// wave g = blockIdx.y*4+wv handles bins g, g+8, ... (<49).
__global__ __launch_bounds__(256) void roi_pool_nhwc(
    const float* __restrict__ nh, const float* __restrict__ rois,
    unsigned short* __restrict__ ph, unsigned short* __restrict__ pl)
{
    const int roi = blockIdx.x;
    const int t   = threadIdx.x;

    __shared__ float s_box[5];
    __shared__ int   s_ix0[16], s_ix1[16], s_iy0[16], s_iy1[16];
    __shared__ float s_wx0[16], s_wx1[16], s_wy0[16], s_wy1[16];

    if (t < 5) s_box[t] = rois[(size_t)roi * 5 + t];
    __syncthreads();

    const int   b   = (int)s_box[0];
    const float bx1 = s_box[1], by1 = s_box[2], bx2 = s_box[3], by2 = s_box[4];

    const float w = bx2 - bx1, h = by2 - by1;
    float kf = floorf(4.0f + log2f(sqrtf(fmaxf(w * h, 1e-6f)) / 224.0f));
    kf = fminf(fmaxf(kf, 2.0f), 5.0f);
    const int lvl    = (int)kf - 2;
    const int stride = 4 << lvl;
    const int H  = 768  / stride;
    const int Wd = 1280 / stride;

    const size_t lvloff = (lvl == 0) ? NHWC_OFF0 : (lvl == 1) ? NHWC_OFF1
                        : (lvl == 2) ? NHWC_OFF2 : NHWC_OFF3;
    const float* base = nh + lvloff + (size_t)b * H * Wd * C_CH;

    if (t < 14) {
        const float x1s = bx1 / (float)stride - 0.5f;
        const float x2s = bx2 / (float)stride - 0.5f;
        const float coord = x1s + (x2s - x1s) * (((float)t + 0.5f) / 14.0f);
        const float valid = (coord > -1.0f && coord < (float)Wd) ? 1.0f : 0.0f;
        const float cc = fminf(fmaxf(coord, 0.0f), (float)(Wd - 1));
        const int i0 = (int)floorf(cc);
        s_ix0[t] = i0; s_ix1[t] = min(i0 + 1, Wd - 1);
        const float fr = cc - (float)i0;
        s_wx0[t] = (1.0f - fr) * valid; s_wx1[t] = fr * valid;
    } else if (t >= 16 && t < 30) {
        const int j = t - 16;
        const float y1s = by1 / (float)stride - 0.5f;
        const float y2s = by2 / (float)stride - 0.5f;
        const float coord = y1s + (y2s - y1s) * (((float)j + 0.5f) / 14.0f);
        const float valid = (coord > -1.0f && coord < (float)H) ? 1.0f : 0.0f;
        const float cc = fminf(fmaxf(coord, 0.0f), (float)(H - 1));
        const int i0 = (int)floorf(cc);
        s_iy0[j] = i0; s_iy1[j] = min(i0 + 1, H - 1);
        const float fr = cc - (float)i0;
        s_wy0[j] = (1.0f - fr) * valid; s_wy1[j] = fr * valid;
    }
    __syncthreads();

    const int wv = t >> 6, lane = t & 63;
    const int g  = blockIdx.y * 4 + wv;
    const int c4 = lane * 4;

    for (int bin = g; bin < 49; bin += 8) {
        const int by = bin / 7, bx = bin - by * 7;
        float ax = 0.0f, ay = 0.0f, az = 0.0f, aw = 0.0f;
        #pragma unroll
        for (int sy = 0; sy < 2; ++sy) {
            const int jy = by * 2 + sy;
            const int y0 = s_iy0[jy], y1 = s_iy1[jy];
            const float a0 = s_wy0[jy], a1 = s_wy1[jy];
            #pragma unroll
            for (int sx = 0; sx < 2; ++sx) {
                const int jx = bx * 2 + sx;
                const int x0 = s_ix0[jx], x1 = s_ix1[jx];
                const float b0 = s_wx0[jx], b1 = s_wx1[jx];
                const float4 p00 = *(const float4*)(base + ((size_t)(y0 * Wd + x0)) * C_CH + c4);
                const float4 p01 = *(const float4*)(base + ((size_t)(y0 * Wd + x1)) * C_CH + c4);
                const float4 p10 = *(const float4*)(base + ((size_t)(y1 * Wd + x0)) * C_CH + c4);
                const float4 p11 = *(const float4*)(base + ((size_t)(y1 * Wd + x1)) * C_CH + c4);
                const float w00 = a0 * b0, w01 = a0 * b1, w10 = a1 * b0, w11 = a1 * b1;
                ax += w00 * p00.x + w01 * p01.x + w10 * p10.x + w11 * p11.x;
                ay += w00 * p00.y + w01 * p01.y + w10 * p10.y + w11 * p11.y;
                az += w00 * p00.z + w01 * p01.z + w10 * p10.z + w11 * p11.z;
                aw += w00 * p00.w + w01 * p01.w + w10 * p10.w + w11 * p11.w;
            }
        }
        const float r0 = ax * 0.25f, r1 = ay * 0.25f, r2 = az * 0.25f, r3 = aw * 0.25f;
        ushort4 hh, ll;
        hh.x = f2bf(r0); ll.x = f2bf(r0 - bf2f(hh.x));
        hh.y = f2bf(r1); ll.y = f2bf(r1 - bf2f(hh.y));
        hh.z = f2bf(r2); ll.z = f2bf(r2 - bf2f(hh.z));
        hh.w = f2bf(r3); ll.w = f2bf(r3 - bf2f(hh.w));
        const size_t d = (size_t)roi * DFEAT + (size_t)bin * C_CH + c4;
        *(ushort4*)(ph + d) = hh;
        *(ushort4*)(pl + d) = ll;
    }
}

// --------------------- ROI ALIGN fallback (NCHW gather) --------------------
__global__ __launch_bounds__(256) void roi_pool_gather(
    const float* __restrict__ fm0, const float* __restrict__ fm1,
    const float* __restrict__ fm2, const float* __restrict__ fm3,
    const float* __restrict__ rois,
    unsigned short* __restrict__ ph, unsigned short* __restrict__ pl)
{
    const int roi = blockIdx.x;
    const int cq  = blockIdx.y;
    const int t   = threadIdx.x;

    __shared__ float s_box[5];
    __shared__ int   s_ix0[16], s_ix1[16], s_iy0[16], s_iy1[16];
    __shared__ float s_wx0[16], s_wx1[16], s_wy0[16], s_wy1[16];

    if (t < 5) s_box[t] = rois[(size_t)roi * 5 + t];
    __syncthreads();

    const int   b   = (int)s_box[0];
    const float bx1 = s_box[1], by1 = s_box[2], bx2 = s_box[3], by2 = s_box[4];

    const float w = bx2 - bx1, h = by2 - by1;
    float kf = floorf(4.0f + log2f(sqrtf(fmaxf(w * h, 1e-6f)) / 224.0f));
    kf = fminf(fmaxf(kf, 2.0f), 5.0f);
    const int lvl    = (int)kf - 2;
    const int stride = 4 << lvl;
    const int H  = 768  / stride;
    const int Wd = 1280 / stride;
    const float* fm = (lvl == 0) ? fm0 : (lvl == 1) ? fm1 : (lvl == 2) ? fm2 : fm3;

    if (t < 14) {
        const float x1s = bx1 / (float)stride - 0.5f;
        const float x2s = bx2 / (float)stride - 0.5f;
        const float coord = x1s + (x2s - x1s) * (((float)t + 0.5f) / 14.0f);
        const float valid = (coord > -1.0f && coord < (float)Wd) ? 1.0f : 0.0f;
        const float cc = fminf(fmaxf(coord, 0.0f), (float)(Wd - 1));
        const int i0 = (int)floorf(cc);
        s_ix0[t] = i0; s_ix1[t] = min(i0 + 1, Wd - 1);
        const float fr = cc - (float)i0;
        s_wx0[t] = (1.0f - fr) * valid; s_wx1[t] = fr * valid;
    } else if (t >= 16 && t < 30) {
        const int j = t - 16;
        const float y1s = by1 / (float)stride - 0.5f;
        const float y2s = by2 / (float)stride - 0.5f;
        const float coord = y1s + (y2s - y1s) * (((float)j + 0.5f) / 14.0f);
        const float valid = (coord > -1.0f && coord < (float)H) ? 1.0f : 0.0f;
        const float cc = fminf(fmaxf(coord, 0.0f), (float)(H - 1));
        const int i0 = (int)floorf(cc);
        s_iy0[j] = i0; s_iy1[j] = min(i0 + 1, H - 1);
        const float fr = cc - (float)i0;
        s_wy0[j] = (1.0f - fr) * valid; s_wy1[j] = fr * valid;
    }
    __syncthreads();

    const int wv = t >> 6, lane = t & 63;
    const int jx = lane & 15, grp = lane >> 4;
    const int xj = min(jx, 13);
    const int x0 = s_ix0[xj], x1 = s_ix1[xj];
    const float wx0 = s_wx0[xj], wx1 = s_wx1[xj];
    const bool xact = (jx < 14);
    const bool wlane = ((grp & 1) == 0) && ((jx & 1) == 0) && xact;

    int   y0r[4], y1r[4];
    float a0r[4], a1r[4];
    bool  yact[4];
    #pragma unroll
    for (int ky = 0; ky < 4; ++ky) {
        const int jy = ky * 4 + grp;
        const int yj = min(jy, 13);
        y0r[ky] = s_iy0[yj]; y1r[ky] = s_iy1[yj];
        a0r[ky] = s_wy0[yj]; a1r[ky] = s_wy1[yj];
        yact[ky] = (jy < 14);
    }

    const size_t hw = (size_t)H * Wd;
    const float* fmb = fm + (size_t)b * C_CH * hw;
    const int c0 = cq * 64 + wv * 16;

    #pragma unroll 2
    for (int ci = 0; ci < 16; ++ci) {
        const int c = c0 + ci;
        const float* fb = fmb + (size_t)c * hw;
        #pragma unroll
        for (int ky = 0; ky < 4; ++ky) {
            const float* r0 = fb + (size_t)y0r[ky] * Wd;
            const float* r1 = fb + (size_t)y1r[ky] * Wd;
            float v = a0r[ky] * (wx0 * r0[x0] + wx1 * r0[x1])
                    + a1r[ky] * (wx0 * r1[x0] + wx1 * r1[x1]);
            if (!xact || !yact[ky]) v = 0.0f;
            v += __shfl_down(v, 1);
            v += __shfl_down(v, 16);
            if (wlane) {
                const int by = ky * 2 + (grp >> 1);
                if (by < 7) {
                    const int bx = jx >> 1;
                    const float r = v * 0.25f;
                    const size_t d = (size_t)roi * DFEAT + (size_t)(by * 7 + bx) * C_CH + c;
                    const unsigned short hh = f2bf(r);
                    ph[d] = hh;
                    pl[d] = f2bf(r - bf2f(hh));
                }
            }
        }
    }
}

// -------------- fc1 weight split + permute to bin-major K ------------------
// w1h/w1l[n][bin*256 + c] = split(fc1_w[n][c*49 + bin]).
// grid (4 c-tiles, 1024 n). 64 channels x 49 bins per tile.
__global__ __launch_bounds__(256) void split_permute_w1(
    const float* __restrict__ w, unsigned short* __restrict__ oh,
    unsigned short* __restrict__ ol)
{
    __shared__ unsigned short sh[3136], sl[3136];

    const int t  = threadIdx.x;
    const int ct = blockIdx.x;   // 0..3
    const int n  = blockIdx.y;

    const float* src = w + (size_t)n * DFEAT + (size_t)ct * 64 * 49;
    for (int e4 = t; e4 < 784; e4 += 256) {
        const float4 v = *(const float4*)(src + e4 * 4);
        unsigned short hx = f2bf(v.x), hy = f2bf(v.y), hz = f2bf(v.z), hw = f2bf(v.w);
        sh[e4 * 4 + 0] = hx; sl[e4 * 4 + 0] = f2bf(v.x - bf2f(hx));
        sh[e4 * 4 + 1] = hy; sl[e4 * 4 + 1] = f2bf(v.y - bf2f(hy));
        sh[e4 * 4 + 2] = hz; sl[e4 * 4 + 2] = f2bf(v.z - bf2f(hz));
        sh[e4 * 4 + 3] = hw; sl[e4 * 4 + 3] = f2bf(v.w - bf2f(hw));
    }
    __syncthreads();

    for (int e = t; e < 3136; e += 256) {
        const int bin = e >> 6, c = e & 63;
        const size_t d = (size_t)n * DFEAT + (size_t)bin * C_CH + ct * 64 + c;
        oh[d] = sh[c * 49 + bin];
        ol[d] = sl[c * 49 + bin];
    }
}

// ------------------------- fp32 -> bf16 hi/lo split -------------------------
__global__ __launch_bounds__(256) void split_fp32_bf16(
    const float* __restrict__ w, unsigned short* __restrict__ h,
    unsigned short* __restrict__ l, int n4)
{
    int i = blockIdx.x * 256 + threadIdx.x;
    const int stride = gridDim.x * 256;
    for (; i < n4; i += stride) {
        const float4 v = *(const float4*)(w + (size_t)i * 4);
        ushort4 hh, ll;
        hh.x = f2bf(v.x); ll.x = f2bf(v.x - bf2f(hh.x));
        hh.y = f2bf(v.y); ll.y = f2bf(v.y - bf2f(hh.y));
        hh.z = f2bf(v.z); ll.z = f2bf(v.z - bf2f(hh.z));
        hh.w = f2bf(v.w); ll.w = f2bf(v.w - bf2f(hh.w));
        *(ushort4*)(h + (size_t)i * 4) = hh;
        *(ushort4*)(l + (size_t)i * 4) = ll;
    }
}

// --------------------------- bf16x3 MFMA GEMM ------------------------------
#define GBM 128
#define GBN 128
#define GBK 32

__global__ __launch_bounds__(256) void gemm_bf16x3(
    const unsigned short* __restrict__ Ah, const unsigned short* __restrict__ Al,
    const unsigned short* __restrict__ Bh, const unsigned short* __restrict__ Bl,
    float* __restrict__ part, int K, int ksplit)
{
    __shared__ __align__(16) unsigned short sAh[GBM * GBK];
    __shared__ __align__(16) unsigned short sAl[GBM * GBK];
    __shared__ __align__(16) unsigned short sBh[GBN * GBK];
    __shared__ __align__(16) unsigned short sBl[GBN * GBK];

    const int t  = threadIdx.x;
    const int bm = blockIdx.y * GBM, bn = blockIdx.x * GBN;
    const int k0 = blockIdx.z * ksplit, k1 = k0 + ksplit;
    const int lane = t & 63, wv = t >> 6;
    const int wr = wv >> 1, wc = wv & 1;
    const int lm = lane & 15, quad = lane >> 4;

    f32x4 acc[4][4] = {};

    const int srow = t >> 2;
    const int skc  = (t & 3) * 8;

    for (int kk = k0; kk < k1; kk += GBK) {
        #pragma unroll
        for (int q = 0; q < 2; ++q) {
            const int row = q * 64 + srow;
            const size_t ga = (size_t)(bm + row) * K + kk + skc;
            const size_t gb = (size_t)(bn + row) * K + kk + skc;
            const int lo = q * 4096 + t * 16;
            g2lds16(Ah + ga, (char*)sAh + lo);
            g2lds16(Al + ga, (char*)sAl + lo);
            g2lds16(Bh + gb, (char*)sBh + lo);
            g2lds16(Bl + gb, (char*)sBl + lo);
        }
        __syncthreads();

        bf16x8 fah[4], fal[4], fbh[4], fbl[4];
        #pragma unroll
        for (int i = 0; i < 4; ++i) {
            fah[i] = *(const bf16x8*)&sAh[(wr * 64 + i * 16 + lm) * GBK + quad * 8];
            fal[i] = *(const bf16x8*)&sAl[(wr * 64 + i * 16 + lm) * GBK + quad * 8];
            fbh[i] = *(const bf16x8*)&sBh[(wc * 64 + i * 16 + lm) * GBK + quad * 8];
            fbl[i] = *(const bf16x8*)&sBl[(wc * 64 + i * 16 + lm) * GBK + quad * 8];
        }
        #pragma unroll
        for (int i = 0; i < 4; ++i)
            #pragma unroll
            for (int j = 0; j < 4; ++j)
                acc[i][j] = __builtin_amdgcn_mfma_f32_16x16x32_bf16(fah[i], fbh[j], acc[i][j], 0, 0, 0);
        #pragma unroll
        for (int i = 0; i < 4; ++i)
            #pragma unroll
            for (int j = 0; j < 4; ++j)
                acc[i][j] = __builtin_amdgcn_mfma_f32_16x16x32_bf16(fah[i], fbl[j], acc[i][j], 0, 0, 0);
        #pragma unroll
        for (int i = 0; i < 4; ++i)
            #pragma unroll
            for (int j = 0; j < 4; ++j)
                acc[i][j] = __builtin_amdgcn_mfma_f32_16x16x32_bf16(fal[i], fbh[j], acc[i][j], 0, 0, 0);
        __syncthreads();
    }

    float* out = part + (size_t)blockIdx.z * (HID * NROIS);
    #pragma unroll
    for (int i = 0; i < 4; ++i) {
        const int mbase = bm + wr * 64 + i * 16 + quad * 4;
        #pragma unroll
        for (int j = 0; j < 4; ++j) {
            const int n = bn + wc * 64 + j * 16 + lm;
            #pragma unroll
            for (int r = 0; r < 4; ++r)
                out[(size_t)(mbase + r) * HID + n] = acc[i][j][r];
        }
    }
}

// -------- split-K reduce + bias + relu (+ optional hi/lo split out) --------
__global__ __launch_bounds__(256) void reduce_bias_relu(
    const float* __restrict__ part, const float* __restrict__ bias,
    int S, int mode, unsigned short* __restrict__ oh,
    unsigned short* __restrict__ ol, float* __restrict__ ofp)
{
    const int i4 = blockIdx.x * 256 + threadIdx.x;
    const size_t off = (size_t)i4 * 4;
    const int n = (int)(off & (HID - 1));
    float4 s = *(const float4*)(part + off);
    for (int z = 1; z < S; ++z) {
        const float4 p = *(const float4*)(part + (size_t)z * HID * NROIS + off);
        s.x += p.x; s.y += p.y; s.z += p.z; s.w += p.w;
    }
    const float4 b = *(const float4*)(bias + n);
    s.x = fmaxf(s.x + b.x, 0.0f);
    s.y = fmaxf(s.y + b.y, 0.0f);
    s.z = fmaxf(s.z + b.z, 0.0f);
    s.w = fmaxf(s.w + b.w, 0.0f);
    if (mode == 0) {
        *(float4*)(ofp + off) = s;
    } else {
        ushort4 hh, ll;
        hh.x = f2bf(s.x); ll.x = f2bf(s.x - bf2f(hh.x));
        hh.y = f2bf(s.y); ll.y = f2bf(s.y - bf2f(hh.y));
        hh.z = f2bf(s.z); ll.z = f2bf(s.z - bf2f(hh.z));
        hh.w = f2bf(s.w); ll.w = f2bf(s.w - bf2f(hh.w));
        *(ushort4*)(oh + off) = hh;
        *(ushort4*)(ol + off) = ll;
    }
}

// ------------------------------ PREDICTOR ----------------------------------
__global__ __launch_bounds__(256) void pred_kernel(
    const float* __restrict__ A, const float* __restrict__ Wm,
    const float* __restrict__ bias, float* __restrict__ out)
{
    const int i = blockIdx.x;
    const int t = threadIdx.x;
    const int j = t & 31;
    const int s = t >> 5;

    __shared__ float red[8][32];

    float acc = 0.0f;
    if (j < NCLS) {
        const float4* a4 = (const float4*)(A  + (size_t)i * HID + s * 128);
        const float4* w4 = (const float4*)(Wm + (size_t)j * HID + s * 128);
        #pragma unroll 8
        for (int q = 0; q < 32; ++q) {
            const float4 a = a4[q], w = w4[q];
            acc += a.x * w.x + a.y * w.y + a.z * w.z + a.w * w.w;
        }
    }
    red[s][j] = acc;
    __syncthreads();
    if (s == 0 && j < NCLS) {
        float v = bias[j];
        #pragma unroll
        for (int q = 0; q < 8; ++q) v += red[q][j];
        out[(size_t)i * NCLS + j] = v;
    }
}

// ------------------------------- LAUNCH ------------------------------------
extern "C" void kernel_launch(void* const* d_in, const int* in_sizes, int n_in,
                              void* d_out, int out_size, void* d_ws, size_t ws_size,
                              hipStream_t stream) {
    (void)in_sizes; (void)n_in; (void)out_size;

    const float* fm0   = (const float*)d_in[0];
    const float* fm1   = (const float*)d_in[1];
    const float* fm2   = (const float*)d_in[2];
    const float* fm3   = (const float*)d_in[3];
    const float* rois  = (const float*)d_in[4];
    const float* fc1_w = (const float*)d_in[5];
    const float* fc1_b = (const float*)d_in[6];
    const float* fc2_w = (const float*)d_in[7];
    const float* fc2_b = (const float*)d_in[8];
    const float* p_w   = (const float*)d_in[9];
    const float* p_b   = (const float*)d_in[10];

    // ---- workspace layout ----
    const size_t SZ_POOL  = (size_t)NROIS * DFEAT * 2;
    const size_t SZ_W1    = (size_t)HID * DFEAT * 2;
    const size_t SZ_W2    = (size_t)HID * HID * 2;
    const size_t SZ_FC1   = (size_t)NROIS * HID * 2;
    const size_t SZ_FC2O  = (size_t)NROIS * HID * 4;
    const size_t SZ_PART1 = (size_t)HID * NROIS * 4;
    const size_t SZ_NHWC  = (size_t)NHWC_TOT * 4;   // 167.1 MB

    const size_t fixed = 2 * SZ_POOL + 2 * SZ_W1 + 2 * SZ_W2 + 2 * SZ_FC1 + SZ_FC2O;

    const int use_nhwc = (ws_size >= fixed + SZ_NHWC + SZ_PART1) ? 1 : 0;
    const size_t avail_part = ws_size - fixed - (use_nhwc ? SZ_NHWC : 0);
    int S1 = 8;
    while (S1 > 1 && (size_t)S1 * SZ_PART1 > avail_part) S1 >>= 1;
    const int S2 = (S1 < 4) ? S1 : 4;

    char* p = (char*)d_ws;
    unsigned short* ph   = (unsigned short*)p; p += SZ_POOL;
    unsigned short* pl   = (unsigned short*)p; p += SZ_POOL;
    unsigned short* w1h  = (unsigned short*)p; p += SZ_W1;
    unsigned short* w1l  = (unsigned short*)p; p += SZ_W1;
    unsigned short* w2h  = (unsigned short*)p; p += SZ_W2;
    unsigned short* w2l  = (unsigned short*)p; p += SZ_W2;
    unsigned short* fc1h = (unsigned short*)p; p += SZ_FC1;
    unsigned short* fc1l = (unsigned short*)p; p += SZ_FC1;
    float* fc2o = (float*)p; p += SZ_FC2O;
    float* part = (float*)p; p += (size_t)S1 * SZ_PART1;
    float* nhwc = (float*)p;

    float* outp = (float*)d_out;

    // 1. weight splits (fc1 permuted to bin-major K) — grid.x = 4 tiles!
    split_permute_w1<<<dim3(4, 1024), 256, 0, stream>>>(fc1_w, w1h, w1l);
    split_fp32_bf16<<<1024, 256, 0, stream>>>(fc2_w, w2h, w2l, HID * HID / 4);

    // 2. roi align -> pooled hi/lo (bin-major K)
    if (use_nhwc) {
        nchw_to_nhwc<<<dim3(5, 192, 8), 256, 0, stream>>>(fm0, nhwc + NHWC_OFF0, 192, 320);
        nchw_to_nhwc<<<dim3(3,  96, 8), 256, 0, stream>>>(fm1, nhwc + NHWC_OFF1,  96, 160);
        nchw_to_nhwc<<<dim3(2,  48, 8), 256, 0, stream>>>(fm2, nhwc + NHWC_OFF2,  48,  80);
        nchw_to_nhwc<<<dim3(1,  24, 8), 256, 0, stream>>>(fm3, nhwc + NHWC_OFF3,  24,  40);
        roi_pool_nhwc<<<dim3(NROIS, 2), 256, 0, stream>>>(nhwc, rois, ph, pl);
    } else {
        roi_pool_gather<<<dim3(NROIS, 4), 256, 0, stream>>>(fm0, fm1, fm2, fm3, rois, ph, pl);
    }

    // 3. fc1 (split-K S1)
    {
        dim3 grid(HID / GBN, NROIS / GBM, S1);
        gemm_bf16x3<<<grid, 256, 0, stream>>>(ph, pl, w1h, w1l, part, DFEAT, DFEAT / S1);
    }
    reduce_bias_relu<<<NROIS * HID / 4 / 256, 256, 0, stream>>>(
        part, fc1_b, S1, 1, fc1h, fc1l, (float*)nullptr);

    // 4. fc2 (split-K S2)
    {
        dim3 grid(HID / GBN, NROIS / GBM, S2);
        gemm_bf16x3<<<grid, 256, 0, stream>>>(fc1h, fc1l, w2h, w2l, part, HID, HID / S2);
    }
    reduce_bias_relu<<<NROIS * HID / 4 / 256, 256, 0, stream>>>(
        part, fc2_b, S2, 0, (unsigned short*)nullptr, (unsigned short*)nullptr, fc2o);

    // 5. predictor
    pred_kernel<<<NROIS, 256, 0, stream>>>(fc2o, p_w, p_b, outp);
}